// Round 3
// baseline (505.259 us; speedup 1.0000x reference)
//
#include <hip/hip_runtime.h>
#include <stdint.h>

#define BB 32
#define SS 2048
#define DD 1024
#define KK 10
#define NCHUNK 64   // sequence chunks in pass1 (32 rows each)

// clang native vector type — required by __builtin_nontemporal_store
// (HIP's float4 is a struct and is rejected). Same 16B layout.
typedef float vf4 __attribute__((ext_vector_type(4)));

// ---- Pass 1: partial sums over sequence dim (fp32 in) ----
// grid 2048 = (b:32) x (sc:64), block 256. Thread t owns float4 dim-slot t.
// 2048 blocks x 4 waves = 32 waves/CU = EXACTLY one full residency pass
// (8 waves/SIMD, HW max) -> max TLP for latency hiding, no second wave.
// Each thread sums 32 rows sequentially -> part[sc][b][d..d+3].
__global__ void __launch_bounds__(256, 8) ew_pass1(const float* __restrict__ hs,
                                                   float* __restrict__ part) {
    int t = threadIdx.x;          // 0..255  -> dims 4t..4t+3
    int blk = blockIdx.x;
    int b = blk >> 6;             // 0..31
    int sc = blk & 63;            // 0..63

    const float4* base = (const float4*)(hs + ((size_t)b * SS + (size_t)sc * 32) * DD) + t;
    float4 acc = make_float4(0.f, 0.f, 0.f, 0.f);
#pragma unroll 8
    for (int r = 0; r < 32; ++r) {
        float4 x = base[(size_t)r * (DD / 4)];
        acc.x += x.x; acc.y += x.y; acc.z += x.z; acc.w += x.w;
    }
    float4* dst = (float4*)(part + ((size_t)sc * BB + b) * DD) + t;
    *dst = acc;
}

// ---- Pass 2: reduce chunks -> v_raw (mean over S) ----
// grid 128, block 256. idx = b*1024 + d. Reads 8 MB (L2-hot), ~5 us.
__global__ void ew_reduce(const float* __restrict__ part, float* __restrict__ vraw) {
    int idx = blockIdx.x * 256 + threadIdx.x;  // 0..32767
    float s = 0.f;
#pragma unroll
    for (int sc = 0; sc < NCHUNK; ++sc)
        s += part[(size_t)sc * (BB * DD) + idx];
    vraw[idx] = s * (1.0f / (float)SS);
}

// ---- Pass 3: whitening stats + attractor snap -> correction c[b][d] ----
// grid 32 (one per batch row b), block 1024 (thread = dim d).
__global__ void ew_stats(const float* __restrict__ vraw, const float* __restrict__ attr,
                         float* __restrict__ cbuf) {
    int d = threadIdx.x;   // 0..1023
    int bb = blockIdx.x;   // 0..31

    // v_raw for all batch rows at this dim (tiny, L2-hot)
    float v[BB];
    float v_own = 0.f;
#pragma unroll
    for (int j = 0; j < BB; ++j) {
        v[j] = vraw[j * DD + d];
        if (j == bb) v_own = v[j];
    }
    float mean = 0.f;
#pragma unroll
    for (int j = 0; j < BB; ++j) mean += v[j];
    mean *= (1.0f / (float)BB);
    float var = 0.f;
#pragma unroll
    for (int j = 0; j < BB; ++j) { float tdv = v[j] - mean; var += tdv * tdv; }
    var *= (1.0f / (float)BB);
    float rstd = rsqrtf(var + 1e-8f);
    float vn = (v_own - mean) * rstd;

    // attractors at this dim
    float a[KK];
#pragma unroll
    for (int k = 0; k < KK; ++k) a[k] = attr[k * DD + d];

    // batched block reduction over d: for each k, [sum a^2, sum vn*a]
    float p[2 * KK];
#pragma unroll
    for (int k = 0; k < KK; ++k) {
        p[2 * k]     = a[k] * a[k];
        p[2 * k + 1] = vn * a[k];
    }
    __shared__ float red[16][2 * KK];
    __shared__ float tot[2 * KK];
    int lane = d & 63, wid = d >> 6;
#pragma unroll
    for (int off = 32; off > 0; off >>= 1) {
#pragma unroll
        for (int j = 0; j < 2 * KK; ++j) p[j] += __shfl_down(p[j], off, 64);
    }
    if (lane == 0) {
#pragma unroll
        for (int j = 0; j < 2 * KK; ++j) red[wid][j] = p[j];
    }
    __syncthreads();
    if (d < 2 * KK) {
        float s = 0.f;
#pragma unroll
        for (int w = 0; w < 16; ++w) s += red[w][d];
        tot[d] = s;
    }
    __syncthreads();

    // per-thread epilogue (redundant across threads, cheap, wave-uniform)
    float bestc = -3.0e38f;
    int bestk = 0;
    float n1s[KK];
#pragma unroll
    for (int k = 0; k < KK; ++k) {
        float s1 = tot[2 * k];          // ||attr_k||^2
        float pd = tot[2 * k + 1];      // v_norm . attr_k
        float n1 = fmaxf(sqrtf(s1), 1e-8f);      // clamped norm (normalize_attractors)
        n1s[k] = n1;
        float s2 = s1 / (n1 * n1);               // ||att_k||^2 after first normalize
        float n2 = fmaxf(sqrtf(s2), 1e-12f);     // F.normalize denom
        float cs = pd / (n1 * n2);
        if (cs > bestc) { bestc = cs; bestk = k; }   // strict > == argmax-first semantics
    }
    float closest = 0.f;
#pragma unroll
    for (int k = 0; k < KK; ++k)
        if (k == bestk) closest = a[k] / n1s[k];     // att[best_idx] (first-normalized)

    float alpha = 0.3f * (1.0f - bestc);
    float delta = fminf(fmaxf(closest - vn, -0.5f), 0.5f);
    float vs = vn + alpha * delta;
    cbuf[bb * DD + d] = vs - v_own;   // (v_snapped - v_raw): the broadcast term
}

// ---- Pass 4: out = hs + c[b][:] broadcast over S (fp32) ----
// grid 2048 = (b:32) x (rc:64, 32 rows each), block 256.
// 2048 blocks = one full residency pass (was 4096 = two sequential passes
// with a cold restart + drain tail in between).
// `out` is written with nontemporal (nt) stores: out is never re-read;
// streaming it past the caches keeps pass1's hs footprint L3-resident.
__global__ void __launch_bounds__(256, 8) ew_apply(const float* __restrict__ hs,
                                                   const float* __restrict__ cbuf,
                                                   float* __restrict__ out) {
    int t = threadIdx.x;          // float4 slot: dims 4t..4t+3
    int blk = blockIdx.x;
    int b = blk >> 6;             // 0..31
    int rc = blk & 63;            // 0..63 -> rows rc*32 .. rc*32+31

    float4 c = ((const float4*)(cbuf + (size_t)b * DD))[t];

    const float4* src = (const float4*)(hs + ((size_t)b * SS + (size_t)rc * 32) * DD) + t;
    vf4* dst = (vf4*)(out + ((size_t)b * SS + (size_t)rc * 32) * DD) + t;
#pragma unroll 8
    for (int r = 0; r < 32; ++r) {
        float4 x = src[(size_t)r * (DD / 4)];
        vf4 y;
        y.x = x.x + c.x; y.y = x.y + c.y; y.z = x.z + c.z; y.w = x.w + c.w;
        __builtin_nontemporal_store(y, &dst[(size_t)r * (DD / 4)]);
    }
}

extern "C" void kernel_launch(void* const* d_in, const int* in_sizes, int n_in,
                              void* d_out, int out_size, void* d_ws, size_t ws_size,
                              hipStream_t stream) {
    const float* hs   = (const float*)d_in[0];   // [32,2048,1024] fp32
    const float* attr = (const float*)d_in[1];   // [10,1024] fp32
    float* out = (float*)d_out;                  // [32,2048,1024] fp32

    float* part = (float*)d_ws;                  // 64*32*1024 fp32 = 8 MB
    float* vraw = part + NCHUNK * BB * DD;       // 32*1024 fp32
    float* cbuf = vraw + BB * DD;                // 32*1024 fp32

    ew_pass1 <<<BB * NCHUNK, 256, 0, stream>>>(hs, part);
    ew_reduce<<<128, 256, 0, stream>>>(part, vraw);
    ew_stats <<<BB, 1024, 0, stream>>>(vraw, attr, cbuf);
    ew_apply <<<BB * 64, 256, 0, stream>>>(hs, cbuf, out);
}

// Round 4
// 486.127 us; speedup vs baseline: 1.0394x; 1.0394x over previous
//
#include <hip/hip_runtime.h>
#include <stdint.h>

#define BB 32
#define SS 2048
#define DD 1024
#define KK 10
#define NCHUNK 16   // sequence chunks in pass1 (128 rows each)

// clang native vector type — required by __builtin_nontemporal_store
// (HIP's float4 is a struct and is rejected). Same 16B layout.
typedef float vf4 __attribute__((ext_vector_type(4)));

// ---- Pass 1: partial sums over sequence dim (fp32 in) ----
// grid 512 = (b:32) x (sc:16), block 256. Thread t owns float4 dim-slot t (4 dims).
// Each thread sums 128 rows FORWARD -> part[sc][b][d..d+3].
// All 512 blocks are co-resident (2 blocks/CU) and advance ~in lockstep, so at
// kernel exit L3 (256 MiB vs 268 MB of hs) holds the LAST ~122 rows of every
// 128-row chunk. ew_apply exploits this by re-reading each chunk BACKWARD.
__global__ void ew_pass1(const float* __restrict__ hs, float* __restrict__ part) {
    int t = threadIdx.x;          // 0..255  -> dims 4t..4t+3
    int blk = blockIdx.x;
    int b = blk >> 4;             // 0..31
    int sc = blk & 15;            // 0..15

    const float4* base = (const float4*)(hs + ((size_t)b * SS + (size_t)sc * 128) * DD) + t;
    float4 acc = make_float4(0.f, 0.f, 0.f, 0.f);
#pragma unroll 8
    for (int r = 0; r < 128; ++r) {
        float4 x = base[(size_t)r * (DD / 4)];
        acc.x += x.x; acc.y += x.y; acc.z += x.z; acc.w += x.w;
    }
    float4* dst = (float4*)(part + ((size_t)sc * BB + b) * DD) + t;
    *dst = acc;
}

// ---- Pass 2: reduce chunks -> v_raw (mean over S) ----
// grid 128, block 256. idx = b*1024 + d. Reads 2 MB (L2/L3-hot), ~3 us.
__global__ void ew_reduce(const float* __restrict__ part, float* __restrict__ vraw) {
    int idx = blockIdx.x * 256 + threadIdx.x;  // 0..32767
    float s = 0.f;
#pragma unroll
    for (int sc = 0; sc < NCHUNK; ++sc)
        s += part[(size_t)sc * (BB * DD) + idx];
    vraw[idx] = s * (1.0f / (float)SS);
}

// ---- Pass 3: whitening stats + attractor snap -> correction c[b][d] ----
// grid 32 (one per batch row b), block 1024 (thread = dim d).
__global__ void ew_stats(const float* __restrict__ vraw, const float* __restrict__ attr,
                         float* __restrict__ cbuf) {
    int d = threadIdx.x;   // 0..1023
    int bb = blockIdx.x;   // 0..31

    // v_raw for all batch rows at this dim (tiny, L2-hot)
    float v[BB];
    float v_own = 0.f;
#pragma unroll
    for (int j = 0; j < BB; ++j) {
        v[j] = vraw[j * DD + d];
        if (j == bb) v_own = v[j];
    }
    float mean = 0.f;
#pragma unroll
    for (int j = 0; j < BB; ++j) mean += v[j];
    mean *= (1.0f / (float)BB);
    float var = 0.f;
#pragma unroll
    for (int j = 0; j < BB; ++j) { float tdv = v[j] - mean; var += tdv * tdv; }
    var *= (1.0f / (float)BB);
    float rstd = rsqrtf(var + 1e-8f);
    float vn = (v_own - mean) * rstd;

    // attractors at this dim
    float a[KK];
#pragma unroll
    for (int k = 0; k < KK; ++k) a[k] = attr[k * DD + d];

    // batched block reduction over d: for each k, [sum a^2, sum vn*a]
    float p[2 * KK];
#pragma unroll
    for (int k = 0; k < KK; ++k) {
        p[2 * k]     = a[k] * a[k];
        p[2 * k + 1] = vn * a[k];
    }
    __shared__ float red[16][2 * KK];
    __shared__ float tot[2 * KK];
    int lane = d & 63, wid = d >> 6;
#pragma unroll
    for (int off = 32; off > 0; off >>= 1) {
#pragma unroll
        for (int j = 0; j < 2 * KK; ++j) p[j] += __shfl_down(p[j], off, 64);
    }
    if (lane == 0) {
#pragma unroll
        for (int j = 0; j < 2 * KK; ++j) red[wid][j] = p[j];
    }
    __syncthreads();
    if (d < 2 * KK) {
        float s = 0.f;
#pragma unroll
        for (int w = 0; w < 16; ++w) s += red[w][d];
        tot[d] = s;
    }
    __syncthreads();

    // per-thread epilogue (redundant across threads, cheap, wave-uniform)
    float bestc = -3.0e38f;
    int bestk = 0;
    float n1s[KK];
#pragma unroll
    for (int k = 0; k < KK; ++k) {
        float s1 = tot[2 * k];          // ||attr_k||^2
        float pd = tot[2 * k + 1];      // v_norm . attr_k
        float n1 = fmaxf(sqrtf(s1), 1e-8f);      // clamped norm (normalize_attractors)
        n1s[k] = n1;
        float s2 = s1 / (n1 * n1);               // ||att_k||^2 after first normalize
        float n2 = fmaxf(sqrtf(s2), 1e-12f);     // F.normalize denom
        float cs = pd / (n1 * n2);
        if (cs > bestc) { bestc = cs; bestk = k; }   // strict > == argmax-first semantics
    }
    float closest = 0.f;
#pragma unroll
    for (int k = 0; k < KK; ++k)
        if (k == bestk) closest = a[k] / n1s[k];     // att[best_idx] (first-normalized)

    float alpha = 0.3f * (1.0f - bestc);
    float delta = fminf(fmaxf(closest - vn, -0.5f), 0.5f);
    float vs = vn + alpha * delta;
    cbuf[bb * DD + d] = vs - v_own;   // (v_snapped - v_raw): the broadcast term
}

// ---- Pass 4: out = hs + c[b][:] broadcast over S (fp32) ----
// grid 512 = (b:32) x (sc:16), block 256 — IDENTICAL decomposition to ew_pass1,
// but each block walks its 128-row chunk in REVERSE (r = 127..0).
// Rationale: hs (268 MB) is ~4.5% bigger than L3 (256 MiB). A forward rescan of
// a slightly-over-capacity working set under recency-based replacement gets ~0%
// hits (the line about to be read was just evicted) — the cyclic-LRU pathology.
// Reading each chunk backward consumes the MOST-recently-cached rows first:
// ~122 of 128 rows per chunk should be L3 hits. nt stores on `out` (never
// re-read) avoid store-allocation evicting the very lines we're about to read.
__global__ void ew_apply(const float* __restrict__ hs, const float* __restrict__ cbuf,
                         float* __restrict__ out) {
    int t = threadIdx.x;          // float4 slot: dims 4t..4t+3
    int blk = blockIdx.x;
    int b = blk >> 4;             // 0..31
    int sc = blk & 15;            // 0..15 -> rows sc*128 .. sc*128+127

    float4 c = ((const float4*)(cbuf + (size_t)b * DD))[t];

    const float4* src = (const float4*)(hs + ((size_t)b * SS + (size_t)sc * 128) * DD) + t;
    vf4* dst = (vf4*)(out + ((size_t)b * SS + (size_t)sc * 128) * DD) + t;
#pragma unroll 8
    for (int r = 127; r >= 0; --r) {
        float4 x = src[(size_t)r * (DD / 4)];
        vf4 y;
        y.x = x.x + c.x; y.y = x.y + c.y; y.z = x.z + c.z; y.w = x.w + c.w;
        __builtin_nontemporal_store(y, &dst[(size_t)r * (DD / 4)]);
    }
}

extern "C" void kernel_launch(void* const* d_in, const int* in_sizes, int n_in,
                              void* d_out, int out_size, void* d_ws, size_t ws_size,
                              hipStream_t stream) {
    const float* hs   = (const float*)d_in[0];   // [32,2048,1024] fp32
    const float* attr = (const float*)d_in[1];   // [10,1024] fp32
    float* out = (float*)d_out;                  // [32,2048,1024] fp32

    float* part = (float*)d_ws;                  // 16*32*1024 fp32 = 2 MB
    float* vraw = part + NCHUNK * BB * DD;       // 32*1024 fp32
    float* cbuf = vraw + BB * DD;                // 32*1024 fp32

    ew_pass1 <<<BB * NCHUNK, 256, 0, stream>>>(hs, part);
    ew_reduce<<<128, 256, 0, stream>>>(part, vraw);
    ew_stats <<<BB, 1024, 0, stream>>>(vraw, attr, cbuf);
    ew_apply <<<BB * NCHUNK, 256, 0, stream>>>(hs, cbuf, out);
}